// Round 1
// 1082.318 us; speedup vs baseline: 1.3940x; 1.3940x over previous
//
#include <hip/hip_runtime.h>

#define B_ 1024
#define L_ 80
#define E_ 256
#define D_ 256
#define T_ 20
#define NS_ 4
#define NSYM_ 100

typedef __attribute__((ext_vector_type(8))) short short8;
typedef __attribute__((ext_vector_type(4))) float f32x4;

__device__ inline short f2b(float f) {
    unsigned u = __float_as_uint(f);
    unsigned r = (u + 0x7fffu + ((u >> 16) & 1u)) >> 16;
    return (short)r;
}
__device__ inline float b2f(short s) {
    return __uint_as_float(((unsigned)(unsigned short)s) << 16);
}

// ---------------- init / conversion kernels ----------------

__global__ void zero_k(unsigned* __restrict__ p, size_t n) {
    size_t i = (size_t)blockIdx.x * blockDim.x + threadIdx.x;
    size_t stride = (size_t)gridDim.x * blockDim.x;
    for (; i < n; i += stride) p[i] = 0u;
}

__global__ void f2b4_k(const float* __restrict__ src, short* __restrict__ dst, size_t n4) {
    size_t i = (size_t)blockIdx.x * blockDim.x + threadIdx.x;
    size_t stride = (size_t)gridDim.x * blockDim.x;
    for (; i < n4; i += stride) {
        float4 v = ((const float4*)src)[i];
        short4 o;
        o.x = f2b(v.x); o.y = f2b(v.y); o.z = f2b(v.z); o.w = f2b(v.w);
        ((short4*)dst)[i] = o;
    }
}

// split W [rows, 512] into two bf16 [rows, 256] halves
__global__ void split_k(const float* __restrict__ Wsrc, short* __restrict__ dstE,
                        short* __restrict__ dstH, int rows) {
    int id = blockIdx.x * 256 + threadIdx.x;
    if (id >= rows * 512) return;
    int rr = id >> 9, cc = id & 511;
    short v = f2b(Wsrc[id]);
    if (cc < 256) dstE[rr * 256 + cc] = v;
    else          dstH[rr * 256 + (cc - 256)] = v;
}

// build gate-interleaved [1024, 512] bf16 weights: row (4u+g) = [Wih[g*256+u,:] | Whh[g*256+u,:]]
__global__ void gatesW_k(const float* __restrict__ Wih, const float* __restrict__ Whh,
                         const float* __restrict__ bih, const float* __restrict__ bhh,
                         short* __restrict__ WgB, float* __restrict__ bg) {
    int id = blockIdx.x * 256 + threadIdx.x;   // < 524288
    int np = id >> 9, cc = id & 511;
    int u = np >> 2, g = np & 3;
    int srow = g * 256 + u;
    float v = (cc < 256) ? Wih[srow * 256 + cc] : Whh[srow * 256 + (cc - 256)];
    WgB[id] = f2b(v);
    if (id < 1024) {
        int u2 = id >> 2, g2 = id & 3;
        bg[id] = bih[g2 * 256 + u2] + bhh[g2 * 256 + u2];
    }
}

// embedding gather -> bf16 embB [T*B, D] with row r = t*B + b
__global__ void embed_k(const int* __restrict__ tsi, const float* __restrict__ common,
                        const float* __restrict__ syms, short* __restrict__ embB) {
    size_t id = (size_t)blockIdx.x * 256 + threadIdx.x;  // < T*B*D
    int d = (int)(id & 255);
    size_t r = id >> 8;
    int tt = (int)(r >> 10);      // B_ = 1024
    int b  = (int)(r & 1023);
    int idx = tsi[b * T_ + tt];
    float v;
    if (idx < NS_) {
        int i2 = idx < 0 ? 0 : idx;
        v = common[i2 * D_ + d];
    } else {
        int i2 = idx - NS_;
        if (i2 > NSYM_ - 1) i2 = NSYM_ - 1;
        v = syms[((size_t)b * NSYM_ + i2) * D_ + d];
    }
    embB[id] = f2b(v);
}

// ---------------- generic bf16 MFMA GEMM: C = act(A @ W^T + addend + bias) ----------------
// A [M, lda] bf16, W [N, K] bf16 row-major. 64x64 tile, 4 waves, each wave 32x32 (2x2 mfma 16x16x32).

__global__ __launch_bounds__(256) void gemm_k(
    const short* __restrict__ A, int lda,
    const short* __restrict__ W,
    const float* __restrict__ addend, int ldAdd,
    const float* __restrict__ bias,
    int act,
    float* __restrict__ outF, int ldoF,
    short* __restrict__ outB, int ldoB,
    int M, int N, int K)
{
    __shared__ alignas(16) short As[64][40];
    __shared__ alignas(16) short Ws[64][40];
    int m0 = blockIdx.x * 64, n0 = blockIdx.y * 64;
    int t = threadIdx.x;
    int w = t >> 6, l = t & 63, quad = l >> 4, lm = l & 15;
    int wm = (w >> 1) * 32, wn = (w & 1) * 32;
    f32x4 acc[2][2] = {};
    int rowL = t >> 2, c8 = (t & 3) * 8;
    for (int k0 = 0; k0 < K; k0 += 32) {
        uint4 av = *(const uint4*)(A + (size_t)(m0 + rowL) * lda + k0 + c8);
        uint4 wv = {0u, 0u, 0u, 0u};
        int wr = n0 + rowL;
        if (wr < N) wv = *(const uint4*)(W + (size_t)wr * K + k0 + c8);
        *(uint4*)&As[rowL][c8] = av;
        *(uint4*)&Ws[rowL][c8] = wv;
        __syncthreads();
        short8 af[2], wf[2];
        af[0] = *(const short8*)&As[wm + lm][quad * 8];
        af[1] = *(const short8*)&As[wm + 16 + lm][quad * 8];
        wf[0] = *(const short8*)&Ws[wn + lm][quad * 8];
        wf[1] = *(const short8*)&Ws[wn + 16 + lm][quad * 8];
        #pragma unroll
        for (int i = 0; i < 2; i++)
            #pragma unroll
            for (int j = 0; j < 2; j++)
                acc[i][j] = __builtin_amdgcn_mfma_f32_16x16x32_bf16(af[i], wf[j], acc[i][j], 0, 0, 0);
        __syncthreads();
    }
    #pragma unroll
    for (int i = 0; i < 2; i++)
        #pragma unroll
        for (int j = 0; j < 2; j++) {
            int col = n0 + wn + j * 16 + lm;
            if (col >= N) continue;
            float bval = bias ? bias[col] : 0.f;
            #pragma unroll
            for (int r = 0; r < 4; r++) {
                int row = m0 + wm + i * 16 + quad * 4 + r;
                float v = acc[i][j][r] + bval;
                if (addend) v += addend[(size_t)row * ldAdd + col];
                if (act == 1) v = fmaxf(v, 0.f);
                if (outF) outF[(size_t)row * ldoF + col] = v;
                if (outB) outB[(size_t)row * ldoB + col] = f2b(v);
            }
        }
}

// ---------------- fused attention + softmax + apply + comb ----------------
// Per block b: aw[l] = awEt[b,l] + h1[b,:]·WaH[l,:]  (awEt already includes emb@WaE^T + b_attn)
// ap = softmax(aw) kept in f32; comb[b,d] = relu(Σ_l ap[l]·encW[b,l,d] + combEt[b,d] + b_comb[d])
// encW = enc @ W_combA^T (precomputed bf16), so no separate apply / comb GEMM needed.

__global__ __launch_bounds__(256) void fused_attn_comb_k(
    const short* __restrict__ h1B,     // [1024, 256] bf16 (H1all slot t)
    const short* __restrict__ WaH,     // [80, 256] bf16
    const float* __restrict__ awEt,    // [1024, 80]  (includes b_attn)
    const short* __restrict__ encW,    // [1024, 80, 256] bf16
    const float* __restrict__ combEt,  // [1024, 256]
    const float* __restrict__ b_comb,  // [256]
    short* __restrict__ X0p)           // write cols 0:256 of [1024, 512]
{
    __shared__ float h1S[256];
    __shared__ float awS[80];
    __shared__ float apS[80];
    int b = blockIdx.x, t = threadIdx.x;
    h1S[t] = b2f(h1B[(size_t)b * 256 + t]);
    __syncthreads();
    float aw = 0.f;
    if (t < 80) {
        const short8* wp = (const short8*)(WaH + (size_t)t * 256);
        float acc = 0.f;
        #pragma unroll 4
        for (int k = 0; k < 32; k++) {
            short8 wv = wp[k];
            const float* hp = &h1S[k * 8];
            acc += hp[0] * b2f(wv[0]) + hp[1] * b2f(wv[1])
                 + hp[2] * b2f(wv[2]) + hp[3] * b2f(wv[3])
                 + hp[4] * b2f(wv[4]) + hp[5] * b2f(wv[5])
                 + hp[6] * b2f(wv[6]) + hp[7] * b2f(wv[7]);
        }
        aw = acc + awEt[(size_t)b * 80 + t];
        awS[t] = aw;
    }
    __syncthreads();
    float mx = -1e30f;
    #pragma unroll 8
    for (int i = 0; i < 80; i++) mx = fmaxf(mx, awS[i]);
    if (t < 80) apS[t] = __expf(aw - mx);
    __syncthreads();
    float s = 0.f;
    #pragma unroll 8
    for (int i = 0; i < 80; i++) s += apS[i];
    float inv = 1.f / s;
    // applied·W already folded into encW: weighted sum, scale by inv at the end
    const short* p = encW + (size_t)b * 80 * 256 + t;
    float acc = 0.f;
    #pragma unroll 8
    for (int l = 0; l < 80; l++) acc += apS[l] * b2f(p[(size_t)l * 256]);
    float v = acc * inv + combEt[(size_t)b * 256 + t] + b_comb[t];
    v = fmaxf(v, 0.f);
    X0p[(size_t)b * 512 + t] = f2b(v);
}

// ---------------- gates GEMM + fused LSTM cell ----------------
// X [1024, 512] bf16 = [x | h_prev]; Wg gate-interleaved [1024, 512]; epilogue updates c, writes h bf16 twice.

__global__ __launch_bounds__(256) void gates_lstm_k(
    const short* __restrict__ X,
    const short* __restrict__ Wg,
    const float* __restrict__ bg,
    float* __restrict__ c,
    short* __restrict__ hA, int ldA, int offA,
    short* __restrict__ hB2, int ldB2, int offB2)
{
    __shared__ alignas(16) short As[64][40];
    __shared__ alignas(16) short Ws[64][40];
    __shared__ float gS[64][68];
    int m0 = blockIdx.x * 64, n0 = blockIdx.y * 64;
    int t = threadIdx.x, w = t >> 6, l = t & 63, quad = l >> 4, lm = l & 15;
    int wm = (w >> 1) * 32, wn = (w & 1) * 32;
    f32x4 acc[2][2] = {};
    int rowL = t >> 2, c8 = (t & 3) * 8;
    for (int k0 = 0; k0 < 512; k0 += 32) {
        *(uint4*)&As[rowL][c8] = *(const uint4*)(X + (size_t)(m0 + rowL) * 512 + k0 + c8);
        *(uint4*)&Ws[rowL][c8] = *(const uint4*)(Wg + (size_t)(n0 + rowL) * 512 + k0 + c8);
        __syncthreads();
        short8 af[2], wf[2];
        af[0] = *(const short8*)&As[wm + lm][quad * 8];
        af[1] = *(const short8*)&As[wm + 16 + lm][quad * 8];
        wf[0] = *(const short8*)&Ws[wn + lm][quad * 8];
        wf[1] = *(const short8*)&Ws[wn + 16 + lm][quad * 8];
        #pragma unroll
        for (int i = 0; i < 2; i++)
            #pragma unroll
            for (int j = 0; j < 2; j++)
                acc[i][j] = __builtin_amdgcn_mfma_f32_16x16x32_bf16(af[i], wf[j], acc[i][j], 0, 0, 0);
        __syncthreads();
    }
    #pragma unroll
    for (int i = 0; i < 2; i++)
        #pragma unroll
        for (int j = 0; j < 2; j++) {
            int col = wn + j * 16 + lm;
            float bval = bg[n0 + col];
            #pragma unroll
            for (int r = 0; r < 4; r++)
                gS[wm + i * 16 + quad * 4 + r][col] = acc[i][j][r] + bval;
        }
    __syncthreads();
    int U0 = n0 >> 2;
    for (int item = t; item < 1024; item += 256) {
        int ml = item >> 4, ul = item & 15;
        float iv = gS[ml][ul * 4 + 0];
        float fv = gS[ml][ul * 4 + 1];
        float gv = gS[ml][ul * 4 + 2];
        float ov = gS[ml][ul * 4 + 3];
        float si = 1.f / (1.f + __expf(-iv));
        float sf = 1.f / (1.f + __expf(-fv));
        float so = 1.f / (1.f + __expf(-ov));
        float tg = tanhf(gv);
        int m = m0 + ml, u = U0 + ul;
        size_t ci = (size_t)m * 256 + u;
        float cn = sf * c[ci] + si * tg;
        float hn = so * tanhf(cn);
        c[ci] = cn;
        short hb = f2b(hn);
        hA[(size_t)m * ldA + offA + u] = hb;
        hB2[(size_t)m * ldB2 + offB2 + u] = hb;
    }
}

// ---------------- batched out GEMM + fused log-softmax ----------------
// logits = h1 @ Wout^T + b_out ; out = logits - max - log(sum exp). M-tile 32, full N=256 per block.
// Run ONCE over all T*B rows after the decode loop (out[t] is not on the serial path).

__global__ __launch_bounds__(256) void out_k(
    const short* __restrict__ h1B,     // [T*B, 256] bf16 (H1all slots 1..T)
    const short* __restrict__ WoB,
    const float* __restrict__ b_out,
    float* __restrict__ outT)          // [T*B, 256]
{
    __shared__ alignas(16) short As[32][40];
    __shared__ alignas(16) short Ws[256][40];
    __shared__ float oS[32][260];
    int m0 = blockIdx.x * 32;
    int t = threadIdx.x, w = t >> 6, l = t & 63, quad = l >> 4, lm = l & 15;
    int wm = (w >> 1) * 16, wn = (w & 1) * 128;
    f32x4 acc[8] = {};
    for (int k0 = 0; k0 < 256; k0 += 32) {
        if (t < 128) {
            int rr = t >> 2, cc = (t & 3) * 8;
            *(uint4*)&As[rr][cc] = *(const uint4*)(h1B + (size_t)(m0 + rr) * 256 + k0 + cc);
        }
        for (int cch = t; cch < 1024; cch += 256) {
            int rr = cch >> 2, cc = (cch & 3) * 8;
            *(uint4*)&Ws[rr][cc] = *(const uint4*)(WoB + (size_t)rr * 256 + k0 + cc);
        }
        __syncthreads();
        short8 af = *(const short8*)&As[wm + lm][quad * 8];
        #pragma unroll
        for (int j = 0; j < 8; j++) {
            short8 wf = *(const short8*)&Ws[wn + j * 16 + lm][quad * 8];
            acc[j] = __builtin_amdgcn_mfma_f32_16x16x32_bf16(af, wf, acc[j], 0, 0, 0);
        }
        __syncthreads();
    }
    #pragma unroll
    for (int j = 0; j < 8; j++)
        #pragma unroll
        for (int r = 0; r < 4; r++)
            oS[wm + quad * 4 + r][wn + j * 16 + lm] = acc[j][r] + b_out[wn + j * 16 + lm];
    __syncthreads();
    int row = t >> 3, q = t & 7;
    float mx = -1e30f;
    for (int i = q * 32; i < q * 32 + 32; i++) mx = fmaxf(mx, oS[row][i]);
    mx = fmaxf(mx, __shfl_xor(mx, 1));
    mx = fmaxf(mx, __shfl_xor(mx, 2));
    mx = fmaxf(mx, __shfl_xor(mx, 4));
    float s = 0.f;
    for (int i = q * 32; i < q * 32 + 32; i++) s += __expf(oS[row][i] - mx);
    s += __shfl_xor(s, 1); s += __shfl_xor(s, 2); s += __shfl_xor(s, 4);
    float lg = mx + logf(s);
    float* orow = outT + (size_t)(m0 + row) * 256;
    for (int i = q * 32; i < q * 32 + 32; i++) orow[i] = oS[row][i] - lg;
}

// ---------------- host ----------------

extern "C" void kernel_launch(void* const* d_in, const int* in_sizes, int n_in,
                              void* d_out, int out_size, void* d_ws, size_t ws_size,
                              hipStream_t stream) {
    const float* encF    = (const float*)d_in[0];
    const float* syms    = (const float*)d_in[1];
    const int*   tsi     = (const int*)d_in[2];
    const float* commonE = (const float*)d_in[3];
    const float* W_attn  = (const float*)d_in[4];
    const float* b_attn  = (const float*)d_in[5];
    const float* W_comb  = (const float*)d_in[6];
    const float* b_comb  = (const float*)d_in[7];
    const float* Wih0    = (const float*)d_in[8];
    const float* Whh0    = (const float*)d_in[9];
    const float* bih0    = (const float*)d_in[10];
    const float* bhh0    = (const float*)d_in[11];
    const float* Wih1    = (const float*)d_in[12];
    const float* Whh1    = (const float*)d_in[13];
    const float* bih1    = (const float*)d_in[14];
    const float* bhh1    = (const float*)d_in[15];
    const float* W_out   = (const float*)d_in[16];
    const float* b_out   = (const float*)d_in[17];
    float* out = (float*)d_out;

    char* base = (char*)d_ws;
    size_t off = 0;
    auto alloc = [&](size_t bytes) -> char* {
        char* p = base + off;
        off += (bytes + 255) & ~(size_t)255;
        return p;
    };
    // zero-region first (contiguous): c0, c1, X0a[:,256:], X1a[:,256:], H1all slot 0
    float* c0    = (float*)alloc((size_t)B_ * D_ * 4);
    float* c1    = (float*)alloc((size_t)B_ * D_ * 4);
    short* X0a   = (short*)alloc((size_t)B_ * 512 * 2);
    short* X1a   = (short*)alloc((size_t)B_ * 512 * 2);
    short* H1all = (short*)alloc((size_t)(T_ + 1) * B_ * D_ * 2);  // slot t = h1 after step t-1
    size_t zeroBytes = (size_t)((char*)H1all - base) + (size_t)B_ * D_ * 2;
    short* X0b   = (short*)alloc((size_t)B_ * 512 * 2);
    short* X1b   = (short*)alloc((size_t)B_ * 512 * 2);
    float* awE   = (float*)alloc((size_t)T_ * B_ * L_ * 4);
    float* combE = (float*)alloc((size_t)T_ * B_ * D_ * 4);
    short* embB  = (short*)alloc((size_t)T_ * B_ * D_ * 2);
    short* WaEB  = (short*)alloc((size_t)L_ * D_ * 2);
    short* WaHB  = (short*)alloc((size_t)L_ * D_ * 2);
    short* WcEB  = (short*)alloc((size_t)D_ * D_ * 2);
    short* WcAB  = (short*)alloc((size_t)D_ * E_ * 2);
    short* Wg0B  = (short*)alloc((size_t)1024 * 512 * 2);
    short* Wg1B  = (short*)alloc((size_t)1024 * 512 * 2);
    short* WoutB = (short*)alloc((size_t)D_ * E_ * 2);
    float* bg0   = (float*)alloc(1024 * 4);
    float* bg1   = (float*)alloc(1024 * 4);
    short* encB  = (short*)alloc((size_t)B_ * L_ * E_ * 2);
    short* encW  = (short*)alloc((size_t)B_ * L_ * D_ * 2);  // enc @ W_combA^T, bf16
    (void)encF; (void)ws_size; (void)in_sizes; (void)n_in; (void)out_size;

    // ---- init / precompute (off the serial path) ----
    zero_k<<<2048, 256, 0, stream>>>((unsigned*)base, zeroBytes / 4);
    f2b4_k<<<4096, 256, 0, stream>>>(encF, encB, (size_t)B_ * L_ * E_ / 4);
    f2b4_k<<<64, 256, 0, stream>>>(W_out, WoutB, (size_t)D_ * E_ / 4);
    split_k<<<(80 * 512) / 256, 256, 0, stream>>>(W_attn, WaEB, WaHB, 80);
    split_k<<<(256 * 512) / 256, 256, 0, stream>>>(W_comb, WcEB, WcAB, 256);
    gatesW_k<<<2048, 256, 0, stream>>>(Wih0, Whh0, bih0, bhh0, Wg0B, bg0);
    gatesW_k<<<2048, 256, 0, stream>>>(Wih1, Whh1, bih1, bhh1, Wg1B, bg1);
    embed_k<<<(T_ * B_ * D_) / 256, 256, 0, stream>>>(tsi, commonE, syms, embB);
    // awE[t,b,l] = emb @ WaE^T + b_attn  (bias folded in here)
    gemm_k<<<dim3(320, 2), 256, 0, stream>>>(embB, 256, WaEB, nullptr, 0, b_attn, 0,
                                             awE, 80, nullptr, 0, 20480, 80, 256);
    // combE[t,b,d] = emb @ WcE^T
    gemm_k<<<dim3(320, 4), 256, 0, stream>>>(embB, 256, WcEB, nullptr, 0, nullptr, 0,
                                             combE, 256, nullptr, 0, 20480, 256, 256);
    // encW[b,l,:] = enc[b,l,:] @ WcA^T  -> lets the comb GEMM leave the decode loop
    gemm_k<<<dim3(1280, 4), 256, 0, stream>>>(encB, 256, WcAB, nullptr, 0, nullptr, 0,
                                              nullptr, 0, encW, 256, 81920, 256, 256);

    // ---- sequential decode: 3 dependent kernels per timestep ----
    for (int tt = 0; tt < T_; tt++) {
        int p = tt & 1;
        short* X0p = p ? X0b : X0a;
        short* X0q = p ? X0a : X0b;
        short* X1p = p ? X1b : X1a;
        short* X1q = p ? X1a : X1b;

        // attn + softmax + apply + comb, fused -> X0p[:, 0:256]
        fused_attn_comb_k<<<1024, 256, 0, stream>>>(
            H1all + (size_t)tt * B_ * D_, WaHB, awE + (size_t)tt * B_ * L_,
            encW, combE + (size_t)tt * B_ * D_, b_comb, X0p);
        // layer 0: reads X0p = [comb | h0_prev]; writes h0 -> X0q[:,256:] (next step), X1p[:,0:256]
        gates_lstm_k<<<dim3(16, 16), 256, 0, stream>>>(X0p, Wg0B, bg0, c0,
                                                       X0q, 512, 256, X1p, 512, 0);
        // layer 1: reads X1p = [h0 | h1_prev]; writes h1 -> X1q[:,256:] (next step), H1all slot tt+1
        gates_lstm_k<<<dim3(16, 16), 256, 0, stream>>>(X1p, Wg1B, bg1, c1,
                                                       X1q, 512, 256,
                                                       H1all + (size_t)(tt + 1) * B_ * D_, 256, 0);
    }
    // ---- batched output projection + log-softmax over all T*B rows ----
    out_k<<<640, 256, 0, stream>>>(H1all + (size_t)B_ * D_, WoutB, b_out, out);
}